// Round 1
// baseline (231.119 us; speedup 1.0000x reference)
//
#include <hip/hip_runtime.h>
#include <hip/hip_bf16.h>
#include <math.h>

#define T_SEQ 4096
#define C_DIM 1024
#define H_HEADS 16
#define D_HEAD 64
#define QKVW 3072
#define WIN_HALF 128
#define GLOBAL_TOK 32

typedef __attribute__((ext_vector_type(8))) short bf16x8;
typedef __attribute__((ext_vector_type(4))) float f32x4;

__device__ __forceinline__ float bf2f(unsigned short u) {
    union { unsigned int i; float f; } c; c.i = ((unsigned int)u) << 16; return c.f;
}
__device__ __forceinline__ unsigned short f2bf(float f) {
    union { float f; unsigned int i; } c; c.f = f;
    return (unsigned short)((c.i + 0x7fffu + ((c.i >> 16) & 1u)) >> 16);
}

__device__ __forceinline__ void gll16(const unsigned short* g, unsigned short* l) {
    __builtin_amdgcn_global_load_lds(
        (const __attribute__((address_space(1))) void*)g,
        (__attribute__((address_space(3))) void*)l, 16, 0, 0);
}

// f32 -> bf16 (RNE), vectorized x4. n4 = n/4.
__global__ __launch_bounds__(256) void cvt_f32_bf16_kernel(
    const float* __restrict__ src, unsigned short* __restrict__ dst, int n4)
{
    int idx = blockIdx.x * 256 + threadIdx.x;
    if (idx < n4) {
        float4 v = ((const float4*)src)[idx];
        ushort4 o;
        o.x = f2bf(v.x); o.y = f2bf(v.y); o.z = f2bf(v.z); o.w = f2bf(v.w);
        ((ushort4*)dst)[idx] = o;
    }
}

// W [R][Ncols] f32  ->  Wt [Ncols][R] bf16  (32x32 tiles via LDS)
__global__ __launch_bounds__(256) void cvt_transpose_kernel(
    const float* __restrict__ src, unsigned short* __restrict__ dst,
    int R, int Ncols)
{
    __shared__ unsigned short tile[32][36];
    const int r0 = blockIdx.y * 32, c0 = blockIdx.x * 32;
    const int t = threadIdx.x;
    const int rr = t >> 3, cq = (t & 7) * 4;
    float4 v = *(const float4*)(src + (size_t)(r0 + rr) * Ncols + c0 + cq);
    tile[rr][cq + 0] = f2bf(v.x); tile[rr][cq + 1] = f2bf(v.y);
    tile[rr][cq + 2] = f2bf(v.z); tile[rr][cq + 3] = f2bf(v.w);
    __syncthreads();
    const int cc = t >> 3, rq = (t & 7) * 4;
    ushort4 o;
    o.x = tile[rq + 0][cc]; o.y = tile[rq + 1][cc];
    o.z = tile[rq + 2][cc]; o.w = tile[rq + 3][cc];
    *(ushort4*)(dst + (size_t)(c0 + cc) * R + r0 + rq) = o;
}

// V slice of qkv [T][2048 + vcol] (bf16) -> vT [vcol][T] (bf16), 32x32 tiles.
__global__ __launch_bounds__(256) void transpose_v_kernel(
    const unsigned short* __restrict__ qkv, unsigned short* __restrict__ vT)
{
    __shared__ unsigned short tile[32][36];
    const int c0 = blockIdx.x * 32;   // vcol
    const int t0 = blockIdx.y * 32;   // token
    const int t = threadIdx.x;
    const int rr = t >> 3, cq = (t & 7) * 4;
    ushort4 v = *(const ushort4*)(qkv + (size_t)(t0 + rr) * QKVW + 2 * C_DIM + c0 + cq);
    tile[rr][cq + 0] = v.x; tile[rr][cq + 1] = v.y;
    tile[rr][cq + 2] = v.z; tile[rr][cq + 3] = v.w;
    __syncthreads();
    const int cc = t >> 3, rq = (t & 7) * 4;
    ushort4 o;
    o.x = tile[rq + 0][cc]; o.y = tile[rq + 1][cc];
    o.z = tile[rq + 2][cc]; o.w = tile[rq + 3][cc];
    *(ushort4*)(vT + (size_t)(c0 + cc) * T_SEQ + t0 + rq) = o;
}

// C[m,n] = sum_k A[m,k]*Bt[n,k] + bias[n]; m97 recipe (unchanged r7-r9).
template<int OUT_BF16>
__global__ __launch_bounds__(256) void gemm_nt_kernel(
    const unsigned short* __restrict__ A,    // [M,K]
    const unsigned short* __restrict__ Bt,   // [N,K]
    const float* __restrict__ bias,          // [N]
    void* __restrict__ Cv, int M, int N, int K)
{
    __shared__ unsigned short As[128 * 32];
    __shared__ unsigned short Bs[128 * 32];
    const int tid = threadIdx.x;
    const int w = tid >> 6, lane = tid & 63;
    const int quad = lane >> 4, r16 = lane & 15;
    const int m0 = blockIdx.y * 128, n0 = blockIdx.x * 128;
    const int wm = (w & 1) * 64, wn = (w >> 1) * 64;

    f32x4 acc[4][4];
    #pragma unroll
    for (int i = 0; i < 4; ++i)
        #pragma unroll
        for (int j = 0; j < 4; ++j) acc[i][j] = (f32x4){0.f, 0.f, 0.f, 0.f};

    const unsigned short* Ab = A + (size_t)m0 * K;
    const unsigned short* Bb = Bt + (size_t)n0 * K;

    for (int k0 = 0; k0 < K; k0 += 32) {
        __syncthreads();
        #pragma unroll
        for (int i = 0; i < 2; ++i) {
            const int chunk = w * 128 + i * 64 + lane;
            const int row = chunk >> 2, kc = (chunk & 3) * 8;
            gll16(Ab + (size_t)row * K + k0 + kc, &As[(w * 2 + i) * 512]);
            gll16(Bb + (size_t)row * K + k0 + kc, &Bs[(w * 2 + i) * 512]);
        }
        asm volatile("s_waitcnt vmcnt(0)" ::: "memory");
        __builtin_amdgcn_sched_barrier(0);
        __syncthreads();

        bf16x8 af[4], bf_[4];
        #pragma unroll
        for (int t = 0; t < 4; ++t) {
            af[t]  = *(const bf16x8*)&As[(wm + t * 16 + r16) * 32 + quad * 8];
            bf_[t] = *(const bf16x8*)&Bs[(wn + t * 16 + r16) * 32 + quad * 8];
        }
        #pragma unroll
        for (int mt = 0; mt < 4; ++mt)
            #pragma unroll
            for (int nt = 0; nt < 4; ++nt)
                acc[mt][nt] = __builtin_amdgcn_mfma_f32_16x16x32_bf16(
                    af[mt], bf_[nt], acc[mt][nt], 0, 0, 0);
    }

    #pragma unroll
    for (int nt = 0; nt < 4; ++nt) {
        const int col = n0 + wn + nt * 16 + r16;
        const float bv = bias[col];
        #pragma unroll
        for (int mt = 0; mt < 4; ++mt)
            #pragma unroll
            for (int reg = 0; reg < 4; ++reg) {
                const int row = m0 + wm + mt * 16 + quad * 4 + reg;
                if (OUT_BF16)
                    ((unsigned short*)Cv)[(size_t)row * N + col] = f2bf(acc[mt][nt][reg] + bv);
                else
                    ((float*)Cv)[(size_t)row * N + col] = acc[mt][nt][reg] + bv;
            }
    }
}

// MFMA flash attention, S^T formulation.
// S^T = K·Q^T (A=K natural rows, B=Q natural rows) -> C-layout col = q-row:
// each lane owns ONE q-row (n=lane&15), 16 score cols (g*16+quad*4+r).
// Softmax: in-lane tree + 2 shfls; single (m,l,alpha) scalar per lane.
// PV: O^T = V^T·P  (A=vT natural, B=P via tiny per-wave LDS round-trip:
// 8 ds_write_b32 + 2 ds_read_b128). O^T C-layout: col=q-row, row=d.
// One wave per (head, 16-row tile), full window sweep (<=7 64-col tiles),
// NO barriers, no cross-wave merge. Dense rows 0-31: 8-way split-K partials
// (slot=split) merged by attn_combine. XCD swizzle: h = bid&15.
// PT_STRIDE = 72 ushorts = 144 B: every row base is a 16B multiple so the
// bf16x8 (b128) LDS reads are legal/aligned for ALL q-rows (68 put odd rows
// at 8-mod-16 addresses = UB). 2-way bank alias (n vs n+8) is free (m136).
#define PT_STRIDE 72
#define NSLOT 8
#define PROW 72
__global__ __launch_bounds__(256, 4) void sparse_attn_mfma(
    const unsigned short* __restrict__ qkv,
    const unsigned short* __restrict__ vT,
    unsigned short* __restrict__ y,
    float* __restrict__ part)
{
    __shared__ unsigned short Pt[4][16 * PT_STRIDE];
    const int tid = threadIdx.x;
    const int w = tid >> 6, lane = tid & 63;
    const int quad = lane >> 4, n = lane & 15;
    const int bid = blockIdx.x;

    int h, rowbase, split = -1, rt = 0;
    if (bid < 1024) {
        h = bid & 15;
        const int rtile = (bid >> 4) * 4 + w;
        if (rtile < 2) return;          // rows 0-31 handled by dense waves
        rowbase = rtile * 16;
    } else {
        const int idx = bid - 1024;     // [0,64)
        h = idx & 15;
        const int u = (idx >> 4) * 4 + w;   // [0,16)
        rt = u >> 3; split = u & 7;
        rowbase = rt * 16;
    }
    const bool dense = split >= 0;

    int wlo = 0, n_tiles;
    if (dense) n_tiles = 8;
    else {
        int t0 = (rowbase - WIN_HALF) & ~63; if (t0 < 64) t0 = 64;
        wlo = t0;
        int whi = rowbase + 16 + WIN_HALF; if (whi > T_SEQ) whi = T_SEQ;
        n_tiles = 1 + (whi - wlo + 63) / 64;
    }

    // Q B-frags: B[n=qrow][k=d] (natural rows)
    const unsigned short* qp = qkv + (size_t)(rowbase + n) * QKVW + h * 64 + quad * 8;
    bf16x8 q0 = *(const bf16x8*)qp;
    bf16x8 q1 = *(const bf16x8*)(qp + 32);

    const unsigned short* kb = qkv + C_DIM + h * 64;
    const unsigned short* vb = vT + (size_t)h * 64 * T_SEQ;
    unsigned short* myPt = Pt[w];

    f32x4 O[4];
    #pragma unroll
    for (int i = 0; i < 4; ++i) O[i] = (f32x4){0.f, 0.f, 0.f, 0.f};
    float m_run = -INFINITY, l_run = 0.f;
    const int row = rowbase + n;

    for (int it = 0; it < n_tiles; ++it) {
        const int c0 = dense ? (split * 512 + it * 64)
                             : (it == 0 ? 0 : wlo + (it - 1) * 64);

        // ---- K A-frags (natural rows): A[m=kcol][k=d] ----
        const unsigned short* kr = kb + (size_t)(c0 + n) * QKVW + quad * 8;
        bf16x8 klo[4], khi[4];
        #pragma unroll
        for (int g = 0; g < 4; ++g) {
            klo[g] = *(const bf16x8*)(kr + (size_t)(g * 16) * QKVW);
            khi[g] = *(const bf16x8*)(kr + (size_t)(g * 16) * QKVW + 32);
        }
        // ---- S^T = K Q^T ----
        const f32x4 Z = (f32x4){0.f, 0.f, 0.f, 0.f};
        f32x4 St[4];
        #pragma unroll
        for (int g = 0; g < 4; ++g) {
            St[g] = __builtin_amdgcn_mfma_f32_16x16x32_bf16(klo[g], q0, Z, 0, 0, 0);
            St[g] = __builtin_amdgcn_mfma_f32_16x16x32_bf16(khi[g], q1, St[g], 0, 0, 0);
        }
        // ---- V^T A-frags (issued early; consumed after softmax) ----
        const unsigned short* vr = vb + (size_t)n * T_SEQ + c0 + quad * 8;
        bf16x8 vlo[4], vhi[4];
        #pragma unroll
        for (int d = 0; d < 4; ++d) {
            vlo[d] = *(const bf16x8*)(vr + (size_t)(d * 16) * T_SEQ);
            vhi[d] = *(const bf16x8*)(vr + (size_t)(d * 16) * T_SEQ + 32);
        }

        // ---- scale + mask (in place) + lane max ----
        float mm = -INFINITY;
        #pragma unroll
        for (int g = 0; g < 4; ++g)
            #pragma unroll
            for (int r = 0; r < 4; ++r) {
                float v = St[g][r] * 0.125f;
                if (!dense) {
                    const int col = c0 + g * 16 + quad * 4 + r;
                    int dd = row - col; dd = dd < 0 ? -dd : dd;
                    if (!(col < GLOBAL_TOK || dd <= WIN_HALF)) v = -INFINITY;
                }
                St[g][r] = v;
                mm = fmaxf(mm, v);
            }
        mm = fmaxf(mm, __shfl_xor(mm, 16));
        mm = fmaxf(mm, __shfl_xor(mm, 32));
        const float mn = fmaxf(m_run, mm);
        const float mnf = (mn == -INFINITY) ? 0.f : mn;
        const float al = __expf(m_run - mnf);
        float rs = 0.f;
        #pragma unroll
        for (int g = 0; g < 4; ++g) {
            float e0 = __expf(St[g][0] - mnf);
            float e1 = __expf(St[g][1] - mnf);
            float e2 = __expf(St[g][2] - mnf);
            float e3 = __expf(St[g][3] - mnf);
            rs += (e0 + e1) + (e2 + e3);
            const unsigned int p01 = f2bf(e0) | ((unsigned int)f2bf(e1) << 16);
            const unsigned int p23 = f2bf(e2) | ((unsigned int)f2bf(e3) << 16);
            *(unsigned int*)&myPt[n * PT_STRIDE + g * 16 + quad * 4] = p01;
            *(unsigned int*)&myPt[n * PT_STRIDE + g * 16 + quad * 4 + 2] = p23;
        }
        rs += __shfl_xor(rs, 16);
        rs += __shfl_xor(rs, 32);
        l_run = l_run * al + rs;
        m_run = mn;
        #pragma unroll
        for (int d = 0; d < 4; ++d)
            #pragma unroll
            for (int r = 0; r < 4; ++r) O[d][r] *= al;

        asm volatile("s_waitcnt lgkmcnt(0)" ::: "memory");
        __builtin_amdgcn_sched_barrier(0);
        // ---- PV: O^T += V^T(A) x P(B) ----
        #pragma unroll
        for (int kg = 0; kg < 2; ++kg) {
            bf16x8 pf = *(const bf16x8*)&myPt[n * PT_STRIDE + kg * 32 + quad * 8];
            #pragma unroll
            for (int d = 0; d < 4; ++d)
                O[d] = __builtin_amdgcn_mfma_f32_16x16x32_bf16(
                    kg ? vhi[d] : vlo[d], pf, O[d], 0, 0, 0);
        }
    }

    if (!dense) {
        const float invL = 1.f / l_run;
        #pragma unroll
        for (int dblk = 0; dblk < 4; ++dblk)
            #pragma unroll
            for (int r = 0; r < 4; ++r)
                y[(size_t)row * C_DIM + h * 64 + dblk * 16 + quad * 4 + r] =
                    f2bf(O[dblk][r] * invL);
    } else {
        float* pb = part + ((size_t)(h * 2 + rt) * NSLOT + split) * 16 * PROW;
        #pragma unroll
        for (int dblk = 0; dblk < 4; ++dblk)
            #pragma unroll
            for (int r = 0; r < 4; ++r)
                pb[n * PROW + dblk * 16 + quad * 4 + r] = O[dblk][r];
        if (quad == 0) {
            pb[n * PROW + 64] = m_run;
            pb[n * PROW + 65] = l_run;
        }
    }
}

// Merge NSLOT partials per (head, 16-row tile) -> y rows 0..31.
__global__ __launch_bounds__(64) void attn_combine(
    const float* __restrict__ part, unsigned short* __restrict__ y)
{
    const int d = threadIdx.x;
    const int h = blockIdx.x >> 1, rt = blockIdx.x & 1;
    const float* base = part + (size_t)(h * 2 + rt) * NSLOT * 16 * PROW;
    for (int row = 0; row < 16; ++row) {
        float M = -INFINITY;
        for (int sl = 0; sl < NSLOT; ++sl)
            M = fmaxf(M, base[(size_t)sl * 16 * PROW + row * PROW + 64]);
        float L = 0.f, Od = 0.f;
        for (int sl = 0; sl < NSLOT; ++sl) {
            const float* p = base + (size_t)sl * 16 * PROW + row * PROW;
            const float s = __expf(p[64] - M);
            L += p[65] * s;
            Od += p[d] * s;
        }
        y[(size_t)(rt * 16 + row) * C_DIM + h * 64 + d] = f2bf(Od / L);
    }
}

extern "C" void kernel_launch(void* const* d_in, const int* in_sizes, int n_in,
                              void* d_out, int out_size, void* d_ws, size_t ws_size,
                              hipStream_t stream) {
    const float* x  = (const float*)d_in[0];
    const float* Wa = (const float*)d_in[1];
    const float* ba = (const float*)d_in[2];
    const float* Wp = (const float*)d_in[3];
    const float* bp = (const float*)d_in[4];
    float* out = (float*)d_out;

    // ws (ushort units): xb 4M, Wabt 3M, Wpbt 1M, qkv 12M, yat 4M = 48 MiB
    unsigned short* xb   = (unsigned short*)d_ws;                   // [4096,1024]
    unsigned short* Wabt = xb   + (size_t)T_SEQ * C_DIM;            // [3072,1024]
    unsigned short* Wpbt = Wabt + (size_t)C_DIM * QKVW;             // [1024,1024]
    unsigned short* qkv  = Wpbt + (size_t)C_DIM * C_DIM;            // [4096,3072]
    unsigned short* yat  = qkv  + (size_t)T_SEQ * QKVW;             // [4096,1024]
    // overlays (dead after gemm1): vT on xb (8 MiB), part on Wabt (2.4 MB)
    unsigned short* vT = xb;
    float* part = (float*)Wabt;

    const int n_x = T_SEQ * C_DIM;
    cvt_f32_bf16_kernel<<<n_x / 4 / 256, 256, 0, stream>>>(x, xb, n_x / 4);
    cvt_transpose_kernel<<<dim3(QKVW / 32, C_DIM / 32), 256, 0, stream>>>(
        Wa, Wabt, C_DIM, QKVW);
    cvt_transpose_kernel<<<dim3(C_DIM / 32, C_DIM / 32), 256, 0, stream>>>(
        Wp, Wpbt, C_DIM, C_DIM);

    gemm_nt_kernel<1><<<dim3(QKVW / 128, T_SEQ / 128), 256, 0, stream>>>(
        xb, Wabt, ba, qkv, T_SEQ, QKVW, C_DIM);

    transpose_v_kernel<<<dim3(C_DIM / 32, T_SEQ / 32), 256, 0, stream>>>(qkv, vT);

    const int nBlocks = 1024 + 64;   // normal + dense split-K
    sparse_attn_mfma<<<nBlocks, 256, 0, stream>>>(qkv, vT, yat, part);
    attn_combine<<<H_HEADS * 2, 64, 0, stream>>>(part, yat);

    gemm_nt_kernel<0><<<dim3(C_DIM / 128, T_SEQ / 128), 256, 0, stream>>>(
        yat, Wpbt, bp, out, T_SEQ, C_DIM, C_DIM);
}

// Round 2
// 224.013 us; speedup vs baseline: 1.0317x; 1.0317x over previous
//
#include <hip/hip_runtime.h>
#include <hip/hip_bf16.h>
#include <math.h>

#define T_SEQ 4096
#define C_DIM 1024
#define H_HEADS 16
#define D_HEAD 64
#define QKVW 3072
#define WIN_HALF 128
#define GLOBAL_TOK 32

typedef __attribute__((ext_vector_type(8))) short bf16x8;
typedef __attribute__((ext_vector_type(4))) float f32x4;

__device__ __forceinline__ float bf2f(unsigned short u) {
    union { unsigned int i; float f; } c; c.i = ((unsigned int)u) << 16; return c.f;
}
__device__ __forceinline__ unsigned short f2bf(float f) {
    union { float f; unsigned int i; } c; c.f = f;
    return (unsigned short)((c.i + 0x7fffu + ((c.i >> 16) & 1u)) >> 16);
}

__device__ __forceinline__ void gll16(const unsigned short* g, unsigned short* l) {
    __builtin_amdgcn_global_load_lds(
        (const __attribute__((address_space(1))) void*)g,
        (__attribute__((address_space(3))) void*)l, 16, 0, 0);
}

// f32 -> bf16 (RNE), vectorized x4. n4 = n/4.
__global__ __launch_bounds__(256) void cvt_f32_bf16_kernel(
    const float* __restrict__ src, unsigned short* __restrict__ dst, int n4)
{
    int idx = blockIdx.x * 256 + threadIdx.x;
    if (idx < n4) {
        float4 v = ((const float4*)src)[idx];
        ushort4 o;
        o.x = f2bf(v.x); o.y = f2bf(v.y); o.z = f2bf(v.z); o.w = f2bf(v.w);
        ((ushort4*)dst)[idx] = o;
    }
}

// W [R][Ncols] f32  ->  Wt [Ncols][R] bf16  (32x32 tiles via LDS)
__global__ __launch_bounds__(256) void cvt_transpose_kernel(
    const float* __restrict__ src, unsigned short* __restrict__ dst,
    int R, int Ncols)
{
    __shared__ unsigned short tile[32][36];
    const int r0 = blockIdx.y * 32, c0 = blockIdx.x * 32;
    const int t = threadIdx.x;
    const int rr = t >> 3, cq = (t & 7) * 4;
    float4 v = *(const float4*)(src + (size_t)(r0 + rr) * Ncols + c0 + cq);
    tile[rr][cq + 0] = f2bf(v.x); tile[rr][cq + 1] = f2bf(v.y);
    tile[rr][cq + 2] = f2bf(v.z); tile[rr][cq + 3] = f2bf(v.w);
    __syncthreads();
    const int cc = t >> 3, rq = (t & 7) * 4;
    ushort4 o;
    o.x = tile[rq + 0][cc]; o.y = tile[rq + 1][cc];
    o.z = tile[rq + 2][cc]; o.w = tile[rq + 3][cc];
    *(ushort4*)(dst + (size_t)(c0 + cc) * R + r0 + rq) = o;
}

// V slice of qkv [T][2048 + vcol] (bf16) -> vT [vcol][T] (bf16), 32x32 tiles.
__global__ __launch_bounds__(256) void transpose_v_kernel(
    const unsigned short* __restrict__ qkv, unsigned short* __restrict__ vT)
{
    __shared__ unsigned short tile[32][36];
    const int c0 = blockIdx.x * 32;   // vcol
    const int t0 = blockIdx.y * 32;   // token
    const int t = threadIdx.x;
    const int rr = t >> 3, cq = (t & 7) * 4;
    ushort4 v = *(const ushort4*)(qkv + (size_t)(t0 + rr) * QKVW + 2 * C_DIM + c0 + cq);
    tile[rr][cq + 0] = v.x; tile[rr][cq + 1] = v.y;
    tile[rr][cq + 2] = v.z; tile[rr][cq + 3] = v.w;
    __syncthreads();
    const int cc = t >> 3, rq = (t & 7) * 4;
    ushort4 o;
    o.x = tile[rq + 0][cc]; o.y = tile[rq + 1][cc];
    o.z = tile[rq + 2][cc]; o.w = tile[rq + 3][cc];
    *(ushort4*)(vT + (size_t)(c0 + cc) * T_SEQ + t0 + rq) = o;
}

// C[m,n] = sum_k A[m,k]*Bt[n,k] + bias[n]; m97 recipe (unchanged).
template<int OUT_BF16>
__global__ __launch_bounds__(256) void gemm_nt_kernel(
    const unsigned short* __restrict__ A,    // [M,K]
    const unsigned short* __restrict__ Bt,   // [N,K]
    const float* __restrict__ bias,          // [N]
    void* __restrict__ Cv, int M, int N, int K)
{
    __shared__ unsigned short As[128 * 32];
    __shared__ unsigned short Bs[128 * 32];
    const int tid = threadIdx.x;
    const int w = tid >> 6, lane = tid & 63;
    const int quad = lane >> 4, r16 = lane & 15;
    const int m0 = blockIdx.y * 128, n0 = blockIdx.x * 128;
    const int wm = (w & 1) * 64, wn = (w >> 1) * 64;

    f32x4 acc[4][4];
    #pragma unroll
    for (int i = 0; i < 4; ++i)
        #pragma unroll
        for (int j = 0; j < 4; ++j) acc[i][j] = (f32x4){0.f, 0.f, 0.f, 0.f};

    const unsigned short* Ab = A + (size_t)m0 * K;
    const unsigned short* Bb = Bt + (size_t)n0 * K;

    for (int k0 = 0; k0 < K; k0 += 32) {
        __syncthreads();
        #pragma unroll
        for (int i = 0; i < 2; ++i) {
            const int chunk = w * 128 + i * 64 + lane;
            const int row = chunk >> 2, kc = (chunk & 3) * 8;
            gll16(Ab + (size_t)row * K + k0 + kc, &As[(w * 2 + i) * 512]);
            gll16(Bb + (size_t)row * K + k0 + kc, &Bs[(w * 2 + i) * 512]);
        }
        asm volatile("s_waitcnt vmcnt(0)" ::: "memory");
        __builtin_amdgcn_sched_barrier(0);
        __syncthreads();

        bf16x8 af[4], bf_[4];
        #pragma unroll
        for (int t = 0; t < 4; ++t) {
            af[t]  = *(const bf16x8*)&As[(wm + t * 16 + r16) * 32 + quad * 8];
            bf_[t] = *(const bf16x8*)&Bs[(wn + t * 16 + r16) * 32 + quad * 8];
        }
        #pragma unroll
        for (int mt = 0; mt < 4; ++mt)
            #pragma unroll
            for (int nt = 0; nt < 4; ++nt)
                acc[mt][nt] = __builtin_amdgcn_mfma_f32_16x16x32_bf16(
                    af[mt], bf_[nt], acc[mt][nt], 0, 0, 0);
    }

    #pragma unroll
    for (int nt = 0; nt < 4; ++nt) {
        const int col = n0 + wn + nt * 16 + r16;
        const float bv = bias[col];
        #pragma unroll
        for (int mt = 0; mt < 4; ++mt)
            #pragma unroll
            for (int reg = 0; reg < 4; ++reg) {
                const int row = m0 + wm + mt * 16 + quad * 4 + reg;
                if (OUT_BF16)
                    ((unsigned short*)Cv)[(size_t)row * N + col] = f2bf(acc[mt][nt][reg] + bv);
                else
                    ((float*)Cv)[(size_t)row * N + col] = acc[mt][nt][reg] + bv;
            }
    }
}

// MFMA flash attention, S^T formulation, K/V register double-buffered.
// S^T = K·Q^T (A=K natural rows, B=Q natural rows) -> col = q-row.
// Per tile: QK (consumes prefetched K) -> issue next tile's K+V loads ->
// mask+softmax (overlaps load latency) -> PV (consumes prefetched V).
// Mask elision: tile fully unmasked iff c0 in [rowbase-113, rowbase+65]
// (covers all 16 rows x 64 cols); dense tiles never masked; global tile
// for rowbase>=192 is exactly {g<2 keep, g>=2 = -inf}.
// PT_STRIDE = 72 ushorts = 144 B: 16B-aligned rows for b128 LDS reads.
#define PT_STRIDE 72
#define NSLOT 8
#define PROW 72

struct KVbuf { bf16x8 kl[4], kh[4], vl[4], vh[4]; };

#define LOAD_KV(C0, B)                                                         \
  {                                                                            \
    const unsigned short* kr_ = kb + (size_t)((C0) + n) * QKVW + quad * 8;     \
    _Pragma("unroll")                                                          \
    for (int g = 0; g < 4; ++g) {                                              \
      B.kl[g] = *(const bf16x8*)(kr_ + (size_t)(g * 16) * QKVW);               \
      B.kh[g] = *(const bf16x8*)(kr_ + (size_t)(g * 16) * QKVW + 32);          \
    }                                                                          \
    const unsigned short* vr_ = vb + (size_t)n * T_SEQ + (C0) + quad * 8;      \
    _Pragma("unroll")                                                          \
    for (int d = 0; d < 4; ++d) {                                              \
      B.vl[d] = *(const bf16x8*)(vr_ + (size_t)(d * 16) * T_SEQ);              \
      B.vh[d] = *(const bf16x8*)(vr_ + (size_t)(d * 16) * T_SEQ + 32);         \
    }                                                                          \
  }

#define PROC_TILE(ITV, CUR, NXT)                                               \
  {                                                                            \
    const int it_ = (ITV);                                                     \
    const int c0 = dense ? (split * 512 + it_ * 64)                            \
                         : (it_ == 0 ? 0 : wlo + (it_ - 1) * 64);              \
    f32x4 St[4];                                                               \
    _Pragma("unroll")                                                          \
    for (int g = 0; g < 4; ++g) {                                              \
      St[g] = __builtin_amdgcn_mfma_f32_16x16x32_bf16(CUR.kl[g], q0, Zf, 0, 0, 0); \
      St[g] = __builtin_amdgcn_mfma_f32_16x16x32_bf16(CUR.kh[g], q1, St[g], 0, 0, 0); \
    }                                                                          \
    if (it_ + 1 < n_tiles) {                                                   \
      const int c0n_ = dense ? (split * 512 + (it_ + 1) * 64)                  \
                             : (it_ == 0 ? wlo : c0 + 64);                     \
      LOAD_KV(c0n_, NXT);                                                      \
    }                                                                          \
    float mm = -INFINITY;                                                      \
    const bool interior_ =                                                     \
        dense || (it_ != 0 && c0 >= rowbase - 113 && c0 <= rowbase + 65);      \
    if (interior_) {                                                           \
      _Pragma("unroll")                                                        \
      for (int g = 0; g < 4; ++g)                                              \
        _Pragma("unroll")                                                      \
        for (int r = 0; r < 4; ++r) {                                          \
          const float v = St[g][r] * 0.125f;                                   \
          St[g][r] = v; mm = fmaxf(mm, v);                                     \
        }                                                                      \
    } else if (it_ == 0 && rowbase >= 192) {                                   \
      _Pragma("unroll")                                                        \
      for (int g = 0; g < 2; ++g)                                              \
        _Pragma("unroll")                                                      \
        for (int r = 0; r < 4; ++r) {                                          \
          const float v = St[g][r] * 0.125f;                                   \
          St[g][r] = v; mm = fmaxf(mm, v);                                     \
        }                                                                      \
      _Pragma("unroll")                                                        \
      for (int g = 2; g < 4; ++g)                                              \
        _Pragma("unroll")                                                      \
        for (int r = 0; r < 4; ++r) St[g][r] = -INFINITY;                      \
    } else {                                                                   \
      _Pragma("unroll")                                                        \
      for (int g = 0; g < 4; ++g)                                              \
        _Pragma("unroll")                                                      \
        for (int r = 0; r < 4; ++r) {                                          \
          float v = St[g][r] * 0.125f;                                         \
          const int col = c0 + g * 16 + quad * 4 + r;                          \
          int dd = row - col; dd = dd < 0 ? -dd : dd;                          \
          if (!(col < GLOBAL_TOK || dd <= WIN_HALF)) v = -INFINITY;            \
          St[g][r] = v; mm = fmaxf(mm, v);                                     \
        }                                                                      \
    }                                                                          \
    mm = fmaxf(mm, __shfl_xor(mm, 16));                                        \
    mm = fmaxf(mm, __shfl_xor(mm, 32));                                        \
    const float mn = fmaxf(m_run, mm);                                         \
    const float mnf = (mn == -INFINITY) ? 0.f : mn;                            \
    const float al = __expf(m_run - mnf);                                      \
    float rs = 0.f;                                                            \
    _Pragma("unroll")                                                          \
    for (int g = 0; g < 4; ++g) {                                              \
      const float e0 = __expf(St[g][0] - mnf);                                 \
      const float e1 = __expf(St[g][1] - mnf);                                 \
      const float e2 = __expf(St[g][2] - mnf);                                 \
      const float e3 = __expf(St[g][3] - mnf);                                 \
      rs += (e0 + e1) + (e2 + e3);                                             \
      const unsigned int p01 = f2bf(e0) | ((unsigned int)f2bf(e1) << 16);      \
      const unsigned int p23 = f2bf(e2) | ((unsigned int)f2bf(e3) << 16);      \
      *(unsigned int*)&myPt[n * PT_STRIDE + g * 16 + quad * 4] = p01;          \
      *(unsigned int*)&myPt[n * PT_STRIDE + g * 16 + quad * 4 + 2] = p23;      \
    }                                                                          \
    rs += __shfl_xor(rs, 16);                                                  \
    rs += __shfl_xor(rs, 32);                                                  \
    l_run = l_run * al + rs;                                                   \
    m_run = mn;                                                                \
    _Pragma("unroll")                                                          \
    for (int d = 0; d < 4; ++d)                                                \
      _Pragma("unroll")                                                        \
      for (int r = 0; r < 4; ++r) O[d][r] *= al;                               \
    asm volatile("s_waitcnt lgkmcnt(0)" ::: "memory");                         \
    __builtin_amdgcn_sched_barrier(0);                                         \
    _Pragma("unroll")                                                          \
    for (int kg = 0; kg < 2; ++kg) {                                           \
      bf16x8 pf_ = *(const bf16x8*)&myPt[n * PT_STRIDE + kg * 32 + quad * 8];  \
      _Pragma("unroll")                                                        \
      for (int d = 0; d < 4; ++d)                                              \
        O[d] = __builtin_amdgcn_mfma_f32_16x16x32_bf16(                        \
            kg ? CUR.vh[d] : CUR.vl[d], pf_, O[d], 0, 0, 0);                   \
    }                                                                          \
  }

__global__ __launch_bounds__(256, 2) void sparse_attn_mfma(
    const unsigned short* __restrict__ qkv,
    const unsigned short* __restrict__ vT,
    unsigned short* __restrict__ y,
    float* __restrict__ part)
{
    __shared__ unsigned short Pt[4][16 * PT_STRIDE];
    const int tid = threadIdx.x;
    const int w = tid >> 6, lane = tid & 63;
    const int quad = lane >> 4, n = lane & 15;
    const int bid = blockIdx.x;

    int h, rowbase, split = -1, rt = 0;
    if (bid < 1024) {
        h = bid & 15;
        const int rtile = (bid >> 4) * 4 + w;
        if (rtile < 2) return;          // rows 0-31 handled by dense waves
        rowbase = rtile * 16;
    } else {
        const int idx = bid - 1024;     // [0,64)
        h = idx & 15;
        const int u = (idx >> 4) * 4 + w;   // [0,16)
        rt = u >> 3; split = u & 7;
        rowbase = rt * 16;
    }
    const bool dense = split >= 0;

    int wlo = 0, n_tiles;
    if (dense) n_tiles = 8;
    else {
        int t0 = (rowbase - WIN_HALF) & ~63; if (t0 < 64) t0 = 64;
        wlo = t0;
        int whi = rowbase + 16 + WIN_HALF; if (whi > T_SEQ) whi = T_SEQ;
        n_tiles = 1 + (whi - wlo + 63) / 64;
    }

    // Q B-frags: B[n=qrow][k=d] (natural rows)
    const unsigned short* qp = qkv + (size_t)(rowbase + n) * QKVW + h * 64 + quad * 8;
    bf16x8 q0 = *(const bf16x8*)qp;
    bf16x8 q1 = *(const bf16x8*)(qp + 32);

    const unsigned short* kb = qkv + C_DIM + h * 64;
    const unsigned short* vb = vT + (size_t)h * 64 * T_SEQ;
    unsigned short* myPt = Pt[w];

    f32x4 O[4];
    #pragma unroll
    for (int i = 0; i < 4; ++i) O[i] = (f32x4){0.f, 0.f, 0.f, 0.f};
    float m_run = -INFINITY, l_run = 0.f;
    const int row = rowbase + n;
    const f32x4 Zf = (f32x4){0.f, 0.f, 0.f, 0.f};

    KVbuf b0, b1;
    {
        const int c00 = dense ? (split * 512) : 0;
        LOAD_KV(c00, b0);
    }
    int it = 0;
    for (;;) {
        PROC_TILE(it, b0, b1);
        if (++it >= n_tiles) break;
        PROC_TILE(it, b1, b0);
        if (++it >= n_tiles) break;
    }

    if (!dense) {
        const float invL = 1.f / l_run;
        #pragma unroll
        for (int dblk = 0; dblk < 4; ++dblk)
            #pragma unroll
            for (int r = 0; r < 4; ++r)
                y[(size_t)row * C_DIM + h * 64 + dblk * 16 + quad * 4 + r] =
                    f2bf(O[dblk][r] * invL);
    } else {
        float* pb = part + ((size_t)(h * 2 + rt) * NSLOT + split) * 16 * PROW;
        #pragma unroll
        for (int dblk = 0; dblk < 4; ++dblk)
            #pragma unroll
            for (int r = 0; r < 4; ++r)
                pb[n * PROW + dblk * 16 + quad * 4 + r] = O[dblk][r];
        if (quad == 0) {
            pb[n * PROW + 64] = m_run;
            pb[n * PROW + 65] = l_run;
        }
    }
}

// Merge NSLOT partials per (head, 16-row tile) -> y rows 0..31.
__global__ __launch_bounds__(64) void attn_combine(
    const float* __restrict__ part, unsigned short* __restrict__ y)
{
    const int d = threadIdx.x;
    const int h = blockIdx.x >> 1, rt = blockIdx.x & 1;
    const float* base = part + (size_t)(h * 2 + rt) * NSLOT * 16 * PROW;
    for (int row = 0; row < 16; ++row) {
        float M = -INFINITY;
        for (int sl = 0; sl < NSLOT; ++sl)
            M = fmaxf(M, base[(size_t)sl * 16 * PROW + row * PROW + 64]);
        float L = 0.f, Od = 0.f;
        for (int sl = 0; sl < NSLOT; ++sl) {
            const float* p = base + (size_t)sl * 16 * PROW + row * PROW;
            const float s = __expf(p[64] - M);
            L += p[65] * s;
            Od += p[d] * s;
        }
        y[(size_t)(rt * 16 + row) * C_DIM + h * 64 + d] = f2bf(Od / L);
    }
}

extern "C" void kernel_launch(void* const* d_in, const int* in_sizes, int n_in,
                              void* d_out, int out_size, void* d_ws, size_t ws_size,
                              hipStream_t stream) {
    const float* x  = (const float*)d_in[0];
    const float* Wa = (const float*)d_in[1];
    const float* ba = (const float*)d_in[2];
    const float* Wp = (const float*)d_in[3];
    const float* bp = (const float*)d_in[4];
    float* out = (float*)d_out;

    // ws (ushort units): xb 4M, Wabt 3M, Wpbt 1M, qkv 12M, yat 4M = 48 MiB
    unsigned short* xb   = (unsigned short*)d_ws;                   // [4096,1024]
    unsigned short* Wabt = xb   + (size_t)T_SEQ * C_DIM;            // [3072,1024]
    unsigned short* Wpbt = Wabt + (size_t)C_DIM * QKVW;             // [1024,1024]
    unsigned short* qkv  = Wpbt + (size_t)C_DIM * C_DIM;            // [4096,3072]
    unsigned short* yat  = qkv  + (size_t)T_SEQ * QKVW;             // [4096,1024]
    // overlays (dead after gemm1): vT on xb (8 MiB), part on Wabt (2.4 MB)
    unsigned short* vT = xb;
    float* part = (float*)Wabt;

    const int n_x = T_SEQ * C_DIM;
    cvt_f32_bf16_kernel<<<n_x / 4 / 256, 256, 0, stream>>>(x, xb, n_x / 4);
    cvt_transpose_kernel<<<dim3(QKVW / 32, C_DIM / 32), 256, 0, stream>>>(
        Wa, Wabt, C_DIM, QKVW);
    cvt_transpose_kernel<<<dim3(C_DIM / 32, C_DIM / 32), 256, 0, stream>>>(
        Wp, Wpbt, C_DIM, C_DIM);

    gemm_nt_kernel<1><<<dim3(QKVW / 128, T_SEQ / 128), 256, 0, stream>>>(
        xb, Wabt, ba, qkv, T_SEQ, QKVW, C_DIM);

    transpose_v_kernel<<<dim3(C_DIM / 32, T_SEQ / 32), 256, 0, stream>>>(qkv, vT);

    const int nBlocks = 1024 + 64;   // normal + dense split-K
    sparse_attn_mfma<<<nBlocks, 256, 0, stream>>>(qkv, vT, yat, part);
    attn_combine<<<H_HEADS * 2, 64, 0, stream>>>(part, yat);

    gemm_nt_kernel<0><<<dim3(C_DIM / 128, T_SEQ / 128), 256, 0, stream>>>(
        yat, Wpbt, bp, out, T_SEQ, C_DIM, C_DIM);
}

// Round 3
// 200.994 us; speedup vs baseline: 1.1499x; 1.1145x over previous
//
#include <hip/hip_runtime.h>
#include <hip/hip_bf16.h>
#include <math.h>

#define T_SEQ 4096
#define C_DIM 1024
#define H_HEADS 16
#define D_HEAD 64
#define QKVW 3072
#define WIN_HALF 128
#define GLOBAL_TOK 32

typedef __attribute__((ext_vector_type(8))) short bf16x8;
typedef __attribute__((ext_vector_type(4))) float f32x4;

__device__ __forceinline__ float bf2f(unsigned short u) {
    union { unsigned int i; float f; } c; c.i = ((unsigned int)u) << 16; return c.f;
}
__device__ __forceinline__ unsigned short f2bf(float f) {
    union { float f; unsigned int i; } c; c.f = f;
    return (unsigned short)((c.i + 0x7fffu + ((c.i >> 16) & 1u)) >> 16);
}

__device__ __forceinline__ void gll16(const unsigned short* g, unsigned short* l) {
    __builtin_amdgcn_global_load_lds(
        (const __attribute__((address_space(1))) void*)g,
        (__attribute__((address_space(3))) void*)l, 16, 0, 0);
}

// XOR-swizzled element offset into a [64][64] bf16 LDS tile.
// chunk in [0,8) selects a 16B (8-elem) granule within the 128B row.
// Swizzle chunk ^= row&7: both the linear staging write (8 rows x 8 chunks
// per wave) and the frag read (16 rows x same chunk) become uniform
// 8 lanes per 4-bank group = the b128 floor rate.
__device__ __forceinline__ int swz(int row, int chunk) {
    return row * 64 + ((chunk ^ (row & 7)) * 8);
}

// f32 -> bf16 (RNE), vectorized x4. n4 = n/4.
__global__ __launch_bounds__(256) void cvt_f32_bf16_kernel(
    const float* __restrict__ src, unsigned short* __restrict__ dst, int n4)
{
    int idx = blockIdx.x * 256 + threadIdx.x;
    if (idx < n4) {
        float4 v = ((const float4*)src)[idx];
        ushort4 o;
        o.x = f2bf(v.x); o.y = f2bf(v.y); o.z = f2bf(v.z); o.w = f2bf(v.w);
        ((ushort4*)dst)[idx] = o;
    }
}

// W [R][Ncols] f32  ->  Wt [Ncols][R] bf16  (32x32 tiles via LDS)
__global__ __launch_bounds__(256) void cvt_transpose_kernel(
    const float* __restrict__ src, unsigned short* __restrict__ dst,
    int R, int Ncols)
{
    __shared__ unsigned short tile[32][36];
    const int r0 = blockIdx.y * 32, c0 = blockIdx.x * 32;
    const int t = threadIdx.x;
    const int rr = t >> 3, cq = (t & 7) * 4;
    float4 v = *(const float4*)(src + (size_t)(r0 + rr) * Ncols + c0 + cq);
    tile[rr][cq + 0] = f2bf(v.x); tile[rr][cq + 1] = f2bf(v.y);
    tile[rr][cq + 2] = f2bf(v.z); tile[rr][cq + 3] = f2bf(v.w);
    __syncthreads();
    const int cc = t >> 3, rq = (t & 7) * 4;
    ushort4 o;
    o.x = tile[rq + 0][cc]; o.y = tile[rq + 1][cc];
    o.z = tile[rq + 2][cc]; o.w = tile[rq + 3][cc];
    *(ushort4*)(dst + (size_t)(c0 + cc) * R + r0 + rq) = o;
}

// V slice of qkv [T][2048 + vcol] (bf16) -> vT [vcol][T] (bf16), 32x32 tiles.
__global__ __launch_bounds__(256) void transpose_v_kernel(
    const unsigned short* __restrict__ qkv, unsigned short* __restrict__ vT)
{
    __shared__ unsigned short tile[32][36];
    const int c0 = blockIdx.x * 32;   // vcol
    const int t0 = blockIdx.y * 32;   // token
    const int t = threadIdx.x;
    const int rr = t >> 3, cq = (t & 7) * 4;
    ushort4 v = *(const ushort4*)(qkv + (size_t)(t0 + rr) * QKVW + 2 * C_DIM + c0 + cq);
    tile[rr][cq + 0] = v.x; tile[rr][cq + 1] = v.y;
    tile[rr][cq + 2] = v.z; tile[rr][cq + 3] = v.w;
    __syncthreads();
    const int cc = t >> 3, rq = (t & 7) * 4;
    ushort4 o;
    o.x = tile[rq + 0][cc]; o.y = tile[rq + 1][cc];
    o.z = tile[rq + 2][cc]; o.w = tile[rq + 3][cc];
    *(ushort4*)(vT + (size_t)(c0 + cc) * T_SEQ + t0 + rq) = o;
}

// C[m,n] = sum_k A[m,k]*Bt[n,k] + bias[n]; m97 recipe (unchanged).
template<int OUT_BF16>
__global__ __launch_bounds__(256) void gemm_nt_kernel(
    const unsigned short* __restrict__ A,    // [M,K]
    const unsigned short* __restrict__ Bt,   // [N,K]
    const float* __restrict__ bias,          // [N]
    void* __restrict__ Cv, int M, int N, int K)
{
    __shared__ unsigned short As[128 * 32];
    __shared__ unsigned short Bs[128 * 32];
    const int tid = threadIdx.x;
    const int w = tid >> 6, lane = tid & 63;
    const int quad = lane >> 4, r16 = lane & 15;
    const int m0 = blockIdx.y * 128, n0 = blockIdx.x * 128;
    const int wm = (w & 1) * 64, wn = (w >> 1) * 64;

    f32x4 acc[4][4];
    #pragma unroll
    for (int i = 0; i < 4; ++i)
        #pragma unroll
        for (int j = 0; j < 4; ++j) acc[i][j] = (f32x4){0.f, 0.f, 0.f, 0.f};

    const unsigned short* Ab = A + (size_t)m0 * K;
    const unsigned short* Bb = Bt + (size_t)n0 * K;

    for (int k0 = 0; k0 < K; k0 += 32) {
        __syncthreads();
        #pragma unroll
        for (int i = 0; i < 2; ++i) {
            const int chunk = w * 128 + i * 64 + lane;
            const int row = chunk >> 2, kc = (chunk & 3) * 8;
            gll16(Ab + (size_t)row * K + k0 + kc, &As[(w * 2 + i) * 512]);
            gll16(Bb + (size_t)row * K + k0 + kc, &Bs[(w * 2 + i) * 512]);
        }
        asm volatile("s_waitcnt vmcnt(0)" ::: "memory");
        __builtin_amdgcn_sched_barrier(0);
        __syncthreads();

        bf16x8 af[4], bf_[4];
        #pragma unroll
        for (int t = 0; t < 4; ++t) {
            af[t]  = *(const bf16x8*)&As[(wm + t * 16 + r16) * 32 + quad * 8];
            bf_[t] = *(const bf16x8*)&Bs[(wn + t * 16 + r16) * 32 + quad * 8];
        }
        #pragma unroll
        for (int mt = 0; mt < 4; ++mt)
            #pragma unroll
            for (int nt = 0; nt < 4; ++nt)
                acc[mt][nt] = __builtin_amdgcn_mfma_f32_16x16x32_bf16(
                    af[mt], bf_[nt], acc[mt][nt], 0, 0, 0);
    }

    #pragma unroll
    for (int nt = 0; nt < 4; ++nt) {
        const int col = n0 + wn + nt * 16 + r16;
        const float bv = bias[col];
        #pragma unroll
        for (int mt = 0; mt < 4; ++mt)
            #pragma unroll
            for (int reg = 0; reg < 4; ++reg) {
                const int row = m0 + wm + mt * 16 + quad * 4 + reg;
                if (OUT_BF16)
                    ((unsigned short*)Cv)[(size_t)row * N + col] = f2bf(acc[mt][nt][reg] + bv);
                else
                    ((float*)Cv)[(size_t)row * N + col] = acc[mt][nt][reg] + bv;
            }
    }
}

// ---------------------------------------------------------------------------
// MFMA flash attention, S^T formulation.
// Windowed blocks (bid<1024): block = (head, 64 consecutive q-rows).
// The 4 waves' windows share one tile list (global tile + [base-128,base+192)),
// so K/V 64x64 tiles are staged into LDS ONCE per block (reg-staged, XOR
// swizzled, double-buffered, 1 barrier/tile, loads issued 1 tile ahead) and
// all 4 waves read frags via ds_read_b128. This cuts global load instructions
// 4x and L2 transactions ~9x vs per-wave register loads (r2: latency-bound,
// 80% idle).
// Dense split-K blocks (bid>=1024, q-rows 0-31): per-wave disjoint K ranges,
// can't share; keep the r2 register double-buffer path.
// PT_STRIDE = 72 ushorts = 144 B: 16B-aligned rows for b128 LDS P reads.
// ---------------------------------------------------------------------------
#define PT_STRIDE 72
#define NSLOT 8
#define PROW 72

struct KVbuf { bf16x8 kl[4], kh[4], vl[4], vh[4]; };
struct StReg { bf16x8 a, b, c, d; };

// ---- dense-path macros (r2, unchanged) ----
#define LOAD_KV(C0, B)                                                         \
  {                                                                            \
    const unsigned short* kr_ = kb + (size_t)((C0) + n) * QKVW + quad * 8;     \
    _Pragma("unroll")                                                          \
    for (int g = 0; g < 4; ++g) {                                              \
      B.kl[g] = *(const bf16x8*)(kr_ + (size_t)(g * 16) * QKVW);               \
      B.kh[g] = *(const bf16x8*)(kr_ + (size_t)(g * 16) * QKVW + 32);          \
    }                                                                          \
    const unsigned short* vr_ = vb + (size_t)n * T_SEQ + (C0) + quad * 8;      \
    _Pragma("unroll")                                                          \
    for (int d = 0; d < 4; ++d) {                                              \
      B.vl[d] = *(const bf16x8*)(vr_ + (size_t)(d * 16) * T_SEQ);              \
      B.vh[d] = *(const bf16x8*)(vr_ + (size_t)(d * 16) * T_SEQ + 32);         \
    }                                                                          \
  }

#define SOFTMAX_P_UPDATE(StV)                                                  \
    mm = fmaxf(mm, __shfl_xor(mm, 16));                                        \
    mm = fmaxf(mm, __shfl_xor(mm, 32));                                        \
    const float mn = fmaxf(m_run, mm);                                         \
    const float mnf = (mn == -INFINITY) ? 0.f : mn;                            \
    const float al = __expf(m_run - mnf);                                      \
    float rs = 0.f;                                                            \
    _Pragma("unroll")                                                          \
    for (int g = 0; g < 4; ++g) {                                              \
      const float e0 = __expf(StV[g][0] - mnf);                                \
      const float e1 = __expf(StV[g][1] - mnf);                                \
      const float e2 = __expf(StV[g][2] - mnf);                                \
      const float e3 = __expf(StV[g][3] - mnf);                                \
      rs += (e0 + e1) + (e2 + e3);                                             \
      const unsigned int p01 = f2bf(e0) | ((unsigned int)f2bf(e1) << 16);      \
      const unsigned int p23 = f2bf(e2) | ((unsigned int)f2bf(e3) << 16);      \
      *(unsigned int*)&myPt[n * PT_STRIDE + g * 16 + quad * 4] = p01;          \
      *(unsigned int*)&myPt[n * PT_STRIDE + g * 16 + quad * 4 + 2] = p23;      \
    }                                                                          \
    rs += __shfl_xor(rs, 16);                                                  \
    rs += __shfl_xor(rs, 32);                                                  \
    l_run = l_run * al + rs;                                                   \
    m_run = mn;                                                                \
    _Pragma("unroll")                                                          \
    for (int d = 0; d < 4; ++d)                                                \
      _Pragma("unroll")                                                        \
      for (int r = 0; r < 4; ++r) O[d][r] *= al;

#define PROC_TILE(ITV, CUR, NXT)                                               \
  {                                                                            \
    const int it_ = (ITV);                                                     \
    const int c0 = split * 512 + it_ * 64;                                     \
    f32x4 St[4];                                                               \
    _Pragma("unroll")                                                          \
    for (int g = 0; g < 4; ++g) {                                              \
      St[g] = __builtin_amdgcn_mfma_f32_16x16x32_bf16(CUR.kl[g], q0, Zf, 0, 0, 0); \
      St[g] = __builtin_amdgcn_mfma_f32_16x16x32_bf16(CUR.kh[g], q1, St[g], 0, 0, 0); \
    }                                                                          \
    if (it_ + 1 < n_tiles) {                                                   \
      LOAD_KV(c0 + 64, NXT);                                                   \
    }                                                                          \
    float mm = -INFINITY;                                                      \
    _Pragma("unroll")                                                          \
    for (int g = 0; g < 4; ++g)                                                \
      _Pragma("unroll")                                                        \
      for (int r = 0; r < 4; ++r) {                                            \
        const float v = St[g][r] * 0.125f;                                     \
        St[g][r] = v; mm = fmaxf(mm, v);                                       \
      }                                                                        \
    SOFTMAX_P_UPDATE(St)                                                       \
    asm volatile("s_waitcnt lgkmcnt(0)" ::: "memory");                         \
    __builtin_amdgcn_sched_barrier(0);                                         \
    _Pragma("unroll")                                                          \
    for (int kg = 0; kg < 2; ++kg) {                                           \
      bf16x8 pf_ = *(const bf16x8*)&myPt[n * PT_STRIDE + kg * 32 + quad * 8];  \
      _Pragma("unroll")                                                        \
      for (int d = 0; d < 4; ++d)                                              \
        O[d] = __builtin_amdgcn_mfma_f32_16x16x32_bf16(                        \
            kg ? CUR.vh[d] : CUR.vl[d], pf_, O[d], 0, 0, 0);                   \
    }                                                                          \
  }

// ---- windowed-path staging macros ----
#define STAGE_LOAD(C0, R)                                                      \
  { const int c0s_ = (C0);                                                     \
    R.a = *(const bf16x8*)(kb + (size_t)(c0s_ + srow) * QKVW + scol * 8);      \
    R.b = *(const bf16x8*)(kb + (size_t)(c0s_ + srow + 32) * QKVW + scol * 8); \
    R.c = *(const bf16x8*)(vb + (size_t)srow * T_SEQ + c0s_ + scol * 8);       \
    R.d = *(const bf16x8*)(vb + (size_t)(srow + 32) * T_SEQ + c0s_ + scol * 8); }

#define STAGE_WRITE(BUF, R)                                                    \
  { *(bf16x8*)&Ks[BUF][kdst0] = R.a;                                           \
    *(bf16x8*)&Ks[BUF][kdst1] = R.b;                                           \
    *(bf16x8*)&Vs[BUF][kdst0] = R.c;                                           \
    *(bf16x8*)&Vs[BUF][kdst1] = R.d; }

#define WTILE(ITV, BUF, RW, RL)                                                \
  {                                                                            \
    const int it_ = (ITV);                                                     \
    const int c0 = (it_ == 0) ? 0 : (blo + (it_ - 1) * 64);                    \
    if (activeW) {                                                             \
      bf16x8 kl[4], kh[4];                                                     \
      _Pragma("unroll")                                                        \
      for (int g = 0; g < 4; ++g) {                                            \
        kl[g] = *(const bf16x8*)&Ks[BUF][swz(n + g * 16, quad)];               \
        kh[g] = *(const bf16x8*)&Ks[BUF][swz(n + g * 16, quad + 4)];           \
      }                                                                        \
      f32x4 St[4];                                                             \
      _Pragma("unroll")                                                        \
      for (int g = 0; g < 4; ++g) {                                            \
        St[g] = __builtin_amdgcn_mfma_f32_16x16x32_bf16(kl[g], q0, Zf, 0, 0, 0); \
        St[g] = __builtin_amdgcn_mfma_f32_16x16x32_bf16(kh[g], q1, St[g], 0, 0, 0); \
      }                                                                        \
      float mm = -INFINITY;                                                    \
      if (it_ != 0 && c0 >= rowbase - 113 && c0 <= rowbase + 65) {             \
        _Pragma("unroll")                                                      \
        for (int g = 0; g < 4; ++g)                                            \
          _Pragma("unroll")                                                    \
          for (int r = 0; r < 4; ++r) {                                        \
            const float v = St[g][r] * 0.125f;                                 \
            St[g][r] = v; mm = fmaxf(mm, v);                                   \
          }                                                                    \
      } else if (it_ == 0 && rowbase >= 192) {                                 \
        _Pragma("unroll")                                                      \
        for (int g = 0; g < 2; ++g)                                            \
          _Pragma("unroll")                                                    \
          for (int r = 0; r < 4; ++r) {                                        \
            const float v = St[g][r] * 0.125f;                                 \
            St[g][r] = v; mm = fmaxf(mm, v);                                   \
          }                                                                    \
        _Pragma("unroll")                                                      \
        for (int g = 2; g < 4; ++g)                                            \
          _Pragma("unroll")                                                    \
          for (int r = 0; r < 4; ++r) St[g][r] = -INFINITY;                    \
      } else {                                                                 \
        _Pragma("unroll")                                                      \
        for (int g = 0; g < 4; ++g)                                            \
          _Pragma("unroll")                                                    \
          for (int r = 0; r < 4; ++r) {                                        \
            float v = St[g][r] * 0.125f;                                       \
            const int col = c0 + g * 16 + quad * 4 + r;                        \
            int dd = row - col; dd = dd < 0 ? -dd : dd;                        \
            if (!(col < GLOBAL_TOK || dd <= WIN_HALF)) v = -INFINITY;          \
            St[g][r] = v; mm = fmaxf(mm, v);                                   \
          }                                                                    \
      }                                                                        \
      SOFTMAX_P_UPDATE(St)                                                     \
      bf16x8 vl[4], vh[4];                                                     \
      _Pragma("unroll")                                                        \
      for (int d = 0; d < 4; ++d) {                                            \
        vl[d] = *(const bf16x8*)&Vs[BUF][swz(n + d * 16, quad)];               \
        vh[d] = *(const bf16x8*)&Vs[BUF][swz(n + d * 16, quad + 4)];           \
      }                                                                        \
      asm volatile("s_waitcnt lgkmcnt(0)" ::: "memory");                       \
      __builtin_amdgcn_sched_barrier(0);                                       \
      _Pragma("unroll")                                                        \
      for (int kg = 0; kg < 2; ++kg) {                                         \
        bf16x8 pf_ = *(const bf16x8*)&myPt[n * PT_STRIDE + kg * 32 + quad * 8];\
        _Pragma("unroll")                                                      \
        for (int d = 0; d < 4; ++d)                                            \
          O[d] = __builtin_amdgcn_mfma_f32_16x16x32_bf16(                      \
              kg ? vh[d] : vl[d], pf_, O[d], 0, 0, 0);                         \
      }                                                                        \
    }                                                                          \
    if (it_ + 1 < NT) {                                                        \
      asm volatile("s_waitcnt vmcnt(0)" ::: "memory");                         \
      __builtin_amdgcn_sched_barrier(0);                                       \
      STAGE_WRITE((BUF) ^ 1, RW);                                              \
      if (it_ + 2 < NT) { STAGE_LOAD(blo + (it_ + 1) * 64, RL); }              \
      __syncthreads();                                                         \
    }                                                                          \
  }

__global__ __launch_bounds__(256, 3) void sparse_attn_mfma(
    const unsigned short* __restrict__ qkv,
    const unsigned short* __restrict__ vT,
    unsigned short* __restrict__ y,
    float* __restrict__ part)
{
    __shared__ unsigned short Ks[2][64 * 64];
    __shared__ unsigned short Vs[2][64 * 64];
    __shared__ unsigned short Pt[4][16 * PT_STRIDE];
    const int tid = threadIdx.x;
    const int w = tid >> 6, lane = tid & 63;
    const int quad = lane >> 4, n = lane & 15;
    const int bid = blockIdx.x;
    const f32x4 Zf = (f32x4){0.f, 0.f, 0.f, 0.f};

    if (bid < 1024) {
        // ---------------- windowed block path ----------------
        const int h = bid & 15;
        const int B = bid >> 4;            // [0,64)
        const int base = B * 64;
        const int rowbase = base + w * 16;
        const bool activeW = !(B == 0 && w < 2);   // rows 0-31 -> dense path
        int blo = base - 128; if (blo < 64) blo = 64;
        int bhi = base + 192; if (bhi > T_SEQ) bhi = T_SEQ;
        const int NT = 1 + (bhi - blo) / 64;

        const unsigned short* kb = qkv + C_DIM + h * 64;
        const unsigned short* vb = vT + (size_t)h * 64 * T_SEQ;
        unsigned short* myPt = Pt[w];

        // staging ids: thread t covers K/V rows srow, srow+32, chunk scol
        const int srow = tid >> 3, scol = tid & 7;
        const int kdst0 = swz(srow, scol);
        const int kdst1 = kdst0 + 32 * 64;

        // Q B-frags
        const unsigned short* qp = qkv + (size_t)(rowbase + n) * QKVW + h * 64 + quad * 8;
        bf16x8 q0 = *(const bf16x8*)qp;
        bf16x8 q1 = *(const bf16x8*)(qp + 32);

        f32x4 O[4];
        #pragma unroll
        for (int i = 0; i < 4; ++i) O[i] = (f32x4){0.f, 0.f, 0.f, 0.f};
        float m_run = -INFINITY, l_run = 0.f;
        const int row = rowbase + n;

        StReg r0, r1;
        STAGE_LOAD(0, r0);                 // tile 0 (global cols)
        asm volatile("s_waitcnt vmcnt(0)" ::: "memory");
        __builtin_amdgcn_sched_barrier(0);
        STAGE_WRITE(0, r0);
        STAGE_LOAD(blo, r1);               // tile 1 (NT >= 3 always)
        __syncthreads();

        int it = 0;
        for (;;) {
            WTILE(it, 0, r1, r0);
            if (++it >= NT) break;
            WTILE(it, 1, r0, r1);
            if (++it >= NT) break;
        }

        if (activeW) {
            const float invL = 1.f / l_run;
            #pragma unroll
            for (int dblk = 0; dblk < 4; ++dblk)
                #pragma unroll
                for (int r = 0; r < 4; ++r)
                    y[(size_t)row * C_DIM + h * 64 + dblk * 16 + quad * 4 + r] =
                        f2bf(O[dblk][r] * invL);
        }
    } else {
        // ---------------- dense split-K path (rows 0-31) ----------------
        const int idx = bid - 1024;        // [0,64)
        const int h = idx & 15;
        const int u = (idx >> 4) * 4 + w;  // [0,16)
        const int rt = u >> 3, split = u & 7;
        const int rowbase = rt * 16;
        const int n_tiles = 8;

        const unsigned short* qp = qkv + (size_t)(rowbase + n) * QKVW + h * 64 + quad * 8;
        bf16x8 q0 = *(const bf16x8*)qp;
        bf16x8 q1 = *(const bf16x8*)(qp + 32);

        const unsigned short* kb = qkv + C_DIM + h * 64;
        const unsigned short* vb = vT + (size_t)h * 64 * T_SEQ;
        unsigned short* myPt = Pt[w];

        f32x4 O[4];
        #pragma unroll
        for (int i = 0; i < 4; ++i) O[i] = (f32x4){0.f, 0.f, 0.f, 0.f};
        float m_run = -INFINITY, l_run = 0.f;

        KVbuf b0, b1;
        LOAD_KV(split * 512, b0);
        int it = 0;
        for (;;) {
            PROC_TILE(it, b0, b1);
            if (++it >= n_tiles) break;
            PROC_TILE(it, b1, b0);
            if (++it >= n_tiles) break;
        }

        float* pb = part + ((size_t)(h * 2 + rt) * NSLOT + split) * 16 * PROW;
        #pragma unroll
        for (int dblk = 0; dblk < 4; ++dblk)
            #pragma unroll
            for (int r = 0; r < 4; ++r)
                pb[n * PROW + dblk * 16 + quad * 4 + r] = O[dblk][r];
        if (quad == 0) {
            pb[n * PROW + 64] = m_run;
            pb[n * PROW + 65] = l_run;
        }
    }
}

// Merge NSLOT partials per (head, 16-row tile) -> y rows 0..31.
__global__ __launch_bounds__(64) void attn_combine(
    const float* __restrict__ part, unsigned short* __restrict__ y)
{
    const int d = threadIdx.x;
    const int h = blockIdx.x >> 1, rt = blockIdx.x & 1;
    const float* base = part + (size_t)(h * 2 + rt) * NSLOT * 16 * PROW;
    for (int row = 0; row < 16; ++row) {
        float M = -INFINITY;
        for (int sl = 0; sl < NSLOT; ++sl)
            M = fmaxf(M, base[(size_t)sl * 16 * PROW + row * PROW + 64]);
        float L = 0.f, Od = 0.f;
        for (int sl = 0; sl < NSLOT; ++sl) {
            const float* p = base + (size_t)sl * 16 * PROW + row * PROW;
            const float s = __expf(p[64] - M);
            L += p[65] * s;
            Od += p[d] * s;
        }
        y[(size_t)(rt * 16 + row) * C_DIM + h * 64 + d] = f2bf(Od / L);
    }
}

extern "C" void kernel_launch(void* const* d_in, const int* in_sizes, int n_in,
                              void* d_out, int out_size, void* d_ws, size_t ws_size,
                              hipStream_t stream) {
    const float* x  = (const float*)d_in[0];
    const float* Wa = (const float*)d_in[1];
    const float* ba = (const float*)d_in[2];
    const float* Wp = (const float*)d_in[3];
    const float* bp = (const float*)d_in[4];
    float* out = (float*)d_out;

    // ws (ushort units): xb 4M, Wabt 3M, Wpbt 1M, qkv 12M, yat 4M = 48 MiB
    unsigned short* xb   = (unsigned short*)d_ws;                   // [4096,1024]
    unsigned short* Wabt = xb   + (size_t)T_SEQ * C_DIM;            // [3072,1024]
    unsigned short* Wpbt = Wabt + (size_t)C_DIM * QKVW;             // [1024,1024]
    unsigned short* qkv  = Wpbt + (size_t)C_DIM * C_DIM;            // [4096,3072]
    unsigned short* yat  = qkv  + (size_t)T_SEQ * QKVW;             // [4096,1024]
    // overlays (dead after gemm1): vT on xb (8 MiB), part on Wabt (2.4 MB)
    unsigned short* vT = xb;
    float* part = (float*)Wabt;

    const int n_x = T_SEQ * C_DIM;
    cvt_f32_bf16_kernel<<<n_x / 4 / 256, 256, 0, stream>>>(x, xb, n_x / 4);
    cvt_transpose_kernel<<<dim3(QKVW / 32, C_DIM / 32), 256, 0, stream>>>(
        Wa, Wabt, C_DIM, QKVW);
    cvt_transpose_kernel<<<dim3(C_DIM / 32, C_DIM / 32), 256, 0, stream>>>(
        Wp, Wpbt, C_DIM, C_DIM);

    gemm_nt_kernel<1><<<dim3(QKVW / 128, T_SEQ / 128), 256, 0, stream>>>(
        xb, Wabt, ba, qkv, T_SEQ, QKVW, C_DIM);

    transpose_v_kernel<<<dim3(C_DIM / 32, T_SEQ / 32), 256, 0, stream>>>(qkv, vT);

    const int nBlocks = 1024 + 64;   // normal + dense split-K
    sparse_attn_mfma<<<nBlocks, 256, 0, stream>>>(qkv, vT, yat, part);
    attn_combine<<<H_HEADS * 2, 64, 0, stream>>>(part, yat);

    gemm_nt_kernel<0><<<dim3(C_DIM / 128, T_SEQ / 128), 256, 0, stream>>>(
        yat, Wpbt, bp, out, T_SEQ, C_DIM, C_DIM);
}